// Round 8
// baseline (399.843 us; speedup 1.0000x reference)
//
#include <hip/hip_runtime.h>
#include <hip/hip_bf16.h>

#define NEG_SLOPE 0.2f
#define EPSF 1e-16f

typedef __attribute__((ext_vector_type(8))) short bf16x8;
typedef __attribute__((ext_vector_type(4))) float f32x4;

__device__ inline unsigned short f2bf(float x) {
  unsigned int u = __float_as_uint(x);
  return (unsigned short)((u + 0x7fffu + ((u >> 16) & 1u)) >> 16);
}
__device__ inline float bf2f(unsigned short h) {
  return __uint_as_float(((unsigned int)h) << 16);
}

__device__ __forceinline__ void gload16(const void* src, void* dst) {
  __builtin_amdgcn_global_load_lds(
      (const __attribute__((address_space(1))) unsigned int*)src,
      (__attribute__((address_space(3))) unsigned int*)dst, 16, 0, 0);
}

// -------------------- W prep: chunked pre-swizzled B slabs --------------------
__global__ __launch_bounds__(256) void prep_w_kernel(const float* __restrict__ W,
                                                     unsigned short* __restrict__ wb) {
  int idx = blockIdx.x * 256 + threadIdx.x;  // (k:512, c:64)
  if (idx >= 512 * 64) return;
  int k = idx >> 6, c = idx & 63;
  float w = W[idx];
  unsigned short h = f2bf(w);
  unsigned short l = f2bf(w - bf2f(h));
  int ch = k >> 5, kin = k & 31;
  int Ap = ((c << 6) + (kin << 1)) ^ ((c & 7) << 4);  // byte in 4KB slab
  wb[ch * 4096 + (Ap >> 1)] = h;
  wb[ch * 4096 + 2048 + (Ap >> 1)] = l;
}

// -------------------- GEMM1 + fused att1: h1b(bf16) = x @ W1; a1s/a1d from f32 acc ----------
__global__ __launch_bounds__(256) void gemm1_kernel(const float* __restrict__ x,
                                                    const unsigned short* __restrict__ wb,
                                                    const float* __restrict__ atts,
                                                    const float* __restrict__ attd,
                                                    unsigned short* __restrict__ h1b,
                                                    float* __restrict__ a1s,
                                                    float* __restrict__ a1d, int N) {
  __shared__ __align__(16) float As[2][4096];          // 2 x 128r x 32k f32 = 32 KB
  __shared__ __align__(16) unsigned short Bs[2][4096]; // 2 x (hi 2048 + lo 2048) = 16 KB
  const int tid = threadIdx.x, wv = tid >> 6, lane = tid & 63;
  const int row0 = blockIdx.x * 128;

  // staging addresses (A source pre-permuted so linear LDS dest == swizzled layout)
  const float* asrc[4];
  int aldo[4];
#pragma unroll
  for (int i = 0; i < 4; ++i) {
    int u = i * 256 + wv * 64 + lane;
    int row = u >> 3, w = u & 7;
    int rg = row0 + row;
    if (rg >= N) rg = N - 1;
    asrc[i] = x + (size_t)rg * 512 + ((w ^ (row & 7)) << 2);
    aldo[i] = (i * 256 + wv * 64) * 4;
  }
  const unsigned short* bsrc[2];
  int bldo[2];
#pragma unroll
  for (int i = 0; i < 2; ++i) {
    int u = i * 256 + wv * 64 + lane;
    bsrc[i] = wb + (size_t)u * 8;
    bldo[i] = (i * 256 + wv * 64) * 8;
  }

  const int kofs = (lane >> 4) * 8;
  const int cbase = lane & 15;
  int ardo[2][2];
#pragma unroll
  for (int rt = 0; rt < 2; ++rt) {
    int r = wv * 32 + rt * 16 + cbase;
#pragma unroll
    for (int h = 0; h < 2; ++h)
      ardo[rt][h] = r * 32 + ((((kofs >> 2) + h) ^ (r & 7)) << 2);
  }
  int brdo[4];
#pragma unroll
  for (int ct = 0; ct < 4; ++ct) {
    int c = ct * 16 + cbase;
    brdo[ct] = (((c << 6) + (kofs << 1)) ^ ((c & 7) << 4)) >> 1;
  }

  f32x4 acc[2][4] = {};

  auto stage = [&](int b, int ch) {
#pragma unroll
    for (int i = 0; i < 4; ++i) gload16(asrc[i] + ch * 32, &As[b][aldo[i]]);
#pragma unroll
    for (int i = 0; i < 2; ++i) gload16(bsrc[i] + ch * 4096, &Bs[b][bldo[i]]);
  };

  stage(0, 0);
  for (int ch = 0; ch < 16; ++ch) {
    const int b = ch & 1;
    if (ch < 15) {
      stage(b ^ 1, ch + 1);
      asm volatile("s_waitcnt vmcnt(6)" ::: "memory");
    } else {
      asm volatile("s_waitcnt vmcnt(0)" ::: "memory");
    }
    __builtin_amdgcn_s_barrier();
    __builtin_amdgcn_sched_barrier(0);

#pragma unroll
    for (int rt = 0; rt < 2; ++rt) {
      float4 a0 = *(const float4*)(&As[b][ardo[rt][0]]);
      float4 a1 = *(const float4*)(&As[b][ardo[rt][1]]);
      float av[8] = {a0.x, a0.y, a0.z, a0.w, a1.x, a1.y, a1.z, a1.w};
      bf16x8 ah, al;
#pragma unroll
      for (int j = 0; j < 8; ++j) {
        unsigned int u = __float_as_uint(av[j]);
        ah[j] = (short)(unsigned short)(u >> 16);
        float lo = av[j] - __uint_as_float(u & 0xffff0000u);
        al[j] = (short)(unsigned short)(__float_as_uint(lo) >> 16);
      }
#pragma unroll
      for (int ct = 0; ct < 4; ++ct) {
        bf16x8 bh = *(const bf16x8*)(&Bs[b][brdo[ct]]);
        bf16x8 bl = *(const bf16x8*)(&Bs[b][brdo[ct] + 2048]);
        acc[rt][ct] = __builtin_amdgcn_mfma_f32_16x16x32_bf16(ah, bh, acc[rt][ct], 0, 0, 0);
        acc[rt][ct] = __builtin_amdgcn_mfma_f32_16x16x32_bf16(al, bh, acc[rt][ct], 0, 0, 0);
        acc[rt][ct] = __builtin_amdgcn_mfma_f32_16x16x32_bf16(ah, bl, acc[rt][ct], 0, 0, 0);
      }
    }
    asm volatile("s_waitcnt lgkmcnt(0)" ::: "memory");
    __builtin_amdgcn_s_barrier();
  }

  // epilogue: h1 bf16 store + fused attention scalars from f32 acc.
  // col c = ct*16+cbase; atts/attd are flat[64] with index c (= head*8 + chan).
  float wS[4], wD[4];
#pragma unroll
  for (int ct = 0; ct < 4; ++ct) {
    wS[ct] = atts[ct * 16 + cbase];
    wD[ct] = attd[ct * 16 + cbase];
  }
#pragma unroll
  for (int rt = 0; rt < 2; ++rt) {
#pragma unroll
    for (int ct = 0; ct < 4; ++ct) {
#pragma unroll
      for (int j = 0; j < 4; ++j) {
        int r = row0 + wv * 32 + rt * 16 + (lane >> 4) * 4 + j;
        float a = acc[rt][ct][j];
        if (r < N) h1b[(size_t)r * 64 + ct * 16 + cbase] = f2bf(a);
        // head-group reduce (8 channels = lane bits 0..2)
        float ps = a * wS[ct], pd = a * wD[ct];
        ps += __shfl_xor(ps, 1); pd += __shfl_xor(pd, 1);
        ps += __shfl_xor(ps, 2); pd += __shfl_xor(pd, 2);
        ps += __shfl_xor(ps, 4); pd += __shfl_xor(pd, 4);
        if ((lane & 7) == 0 && r < N) {
          int h = ct * 2 + ((lane >> 3) & 1);
          a1s[r * 8 + h] = ps;
          a1d[r * 8 + h] = pd;
        }
      }
    }
  }
}

// -------------------- CSR build --------------------
__global__ __launch_bounds__(256) void init_deg_kernel(int* __restrict__ deg, int N) {
  int i = blockIdx.x * 256 + threadIdx.x;
  if (i < N) deg[i] = 1;  // self-loop
}

__global__ __launch_bounds__(256) void count_kernel(const int* __restrict__ ei, int E, int* __restrict__ deg) {
  int e = blockIdx.x * 256 + threadIdx.x;
  if (e < E) atomicAdd(&deg[ei[E + e]], 1);
}

__global__ __launch_bounds__(256) void scan1_kernel(int* __restrict__ data, int* __restrict__ blocksum, int N) {
  __shared__ int wave_tot[4];
  int t = threadIdx.x;
  int base = blockIdx.x * 1024;
  int v[4];
  int sum = 0;
#pragma unroll
  for (int i = 0; i < 4; ++i) {
    int idx = base + t * 4 + i;
    v[i] = sum;
    int d = (idx < N) ? data[idx] : 0;
    sum += d;
  }
  int lane = t & 63, wv = t >> 6;
  int x = sum;
#pragma unroll
  for (int ofs = 1; ofs < 64; ofs <<= 1) {
    int y = __shfl_up(x, ofs);
    if (lane >= ofs) x += y;
  }
  if (lane == 63) wave_tot[wv] = x;
  __syncthreads();
  int wofs = 0;
  for (int w = 0; w < wv; ++w) wofs += wave_tot[w];
  int excl_thread = wofs + x - sum;
#pragma unroll
  for (int i = 0; i < 4; ++i) {
    int idx = base + t * 4 + i;
    if (idx < N) data[idx] = excl_thread + v[i];
  }
  if (t == 255) blocksum[blockIdx.x] = wofs + x;
}

__global__ __launch_bounds__(256) void scan2_kernel(int* __restrict__ blocksum, int nb) {
  __shared__ int sm[256];
  int t = threadIdx.x;
  int x = (t < nb) ? blocksum[t] : 0;
  sm[t] = x;
  __syncthreads();
  for (int ofs = 1; ofs < 256; ofs <<= 1) {
    int y = (t >= ofs) ? sm[t - ofs] : 0;
    __syncthreads();
    sm[t] += y;
    __syncthreads();
  }
  if (t < nb) blocksum[t] = sm[t] - x;  // exclusive
}

__global__ __launch_bounds__(256) void scan3_kernel(const int* __restrict__ excl, const int* __restrict__ blocksum,
                                                    int* __restrict__ rowptr, int* __restrict__ cursor,
                                                    int N, int ET) {
  int idx = blockIdx.x * 256 + threadIdx.x;
  if (idx < N) {
    int r = excl[idx] + blocksum[idx >> 10];
    rowptr[idx] = r;
    cursor[idx] = r;
  }
  if (idx == N) rowptr[N] = ET;
}

// XCD-class-filtered scatter (keeps cursor/esrc writes XCD-local)
__global__ __launch_bounds__(256) void scatter_kernel(const int* __restrict__ ei, int E, int ET,
                                                      int* __restrict__ cursor, int* __restrict__ esrc, int N) {
  const int cls = blockIdx.x & 7;
  const int nlo = (int)(((long long)N * cls) >> 3);
  const int nhi = (int)(((long long)N * (cls + 1)) >> 3);
  const int chunk = blockIdx.x >> 3;
  const int nchunks = gridDim.x >> 3;
  const long long stride = (long long)nchunks * 256;
  for (long long e = (long long)chunk * 256 + threadIdx.x; e < ET; e += stride) {
    int s, d;
    if (e < E) { d = ei[E + e]; s = ei[e]; }
    else       { d = (int)(e - E); s = d; }
    if (d >= nlo && d < nhi) {
      int pos = atomicAdd(&cursor[d], 1);
      esrc[pos] = s;
    }
  }
}

// -------------------- agg1 + fused l2_proj: wave per dst node, lane = channel ----------
// aggregates layer-1, applies norm+bias+ELU in registers (h2 never materialized),
// then g = h2 @ W2 via full-wave butterfly; writes g (bf16), a2s, a2d.
__global__ __launch_bounds__(256) void agg1_kernel(const int* __restrict__ rowptr, const int* __restrict__ esrc,
                                                   const float* __restrict__ a1s, const float* __restrict__ a1d,
                                                   const unsigned short* __restrict__ h1b,
                                                   const float* __restrict__ bias1,
                                                   const float* __restrict__ W2,
                                                   const float* __restrict__ atts2,
                                                   const float* __restrict__ attd2,
                                                   unsigned short* __restrict__ gb,
                                                   float* __restrict__ a2s, float* __restrict__ a2d, int N) {
  int wid = (blockIdx.x * 256 + threadIdx.x) >> 6;
  int lane = threadIdx.x & 63;
  if (wid >= N) return;
  int n = wid;
  int h = lane >> 3;
  // per-lane W2 row (lane = k), 16 coefs
  float w2v[16];
#pragma unroll
  for (int i = 0; i < 4; ++i) {
    float4 t = *(const float4*)(W2 + lane * 16 + i * 4);
    w2v[i * 4 + 0] = t.x; w2v[i * 4 + 1] = t.y; w2v[i * 4 + 2] = t.z; w2v[i * 4 + 3] = t.w;
  }
  float ad = a1d[n * 8 + h];
  int beg = rowptr[n], end = rowptr[n + 1];
  float acc = 0.f, wsum = 0.f;
  int k = beg;
  for (; k + 1 < end; k += 2) {
    int s0 = esrc[k], s1 = esrc[k + 1];
    float al0 = a1s[s0 * 8 + h] + ad;
    float al1 = a1s[s1 * 8 + h] + ad;
    float g0 = bf2f(h1b[(size_t)s0 * 64 + lane]);
    float g1 = bf2f(h1b[(size_t)s1 * 64 + lane]);
    al0 = (al0 > 0.f) ? al0 : NEG_SLOPE * al0;
    al1 = (al1 > 0.f) ? al1 : NEG_SLOPE * al1;
    float w0 = __expf(al0), w1 = __expf(al1);
    acc = fmaf(w0, g0, acc);
    acc = fmaf(w1, g1, acc);
    wsum += w0 + w1;
  }
  if (k < end) {
    int s0 = esrc[k];
    float al0 = a1s[s0 * 8 + h] + ad;
    float g0 = bf2f(h1b[(size_t)s0 * 64 + lane]);
    al0 = (al0 > 0.f) ? al0 : NEG_SLOPE * al0;
    float w0 = __expf(al0);
    acc = fmaf(w0, g0, acc);
    wsum += w0;
  }
  float v = acc / (wsum + EPSF) + bias1[lane];
  v = (v > 0.f) ? v : expm1f(v);  // h2 value for channel=lane, in-register only

  // l2 projection: p[c] = sum_k v_k * W2[k][c] via butterfly over all 64 lanes
  float p[16];
#pragma unroll
  for (int c = 0; c < 16; ++c) p[c] = v * w2v[c];
#pragma unroll
  for (int ofs = 1; ofs < 64; ofs <<= 1) {
#pragma unroll
    for (int c = 0; c < 16; ++c) p[c] += __shfl_xor(p[c], ofs);
  }
  // write g (bf16): lane c<16 writes channel c (selection chain keeps static indexing)
  if (lane < 16) {
    float out = p[0];
#pragma unroll
    for (int c = 1; c < 16; ++c) out = (lane == c) ? p[c] : out;
    gb[(size_t)n * 16 + lane] = f2bf(out);
  }
  if (lane == 0) {
    float ps = 0.f, pd = 0.f;
#pragma unroll
    for (int c = 0; c < 16; ++c) {
      ps = fmaf(p[c], atts2[c], ps);
      pd = fmaf(p[c], attd2[c], pd);
    }
    a2s[n] = ps;
    a2d[n] = pd;
  }
}

// -------------------- layer-2 aggregation + bias + softmax (fused final) --------------------
__global__ __launch_bounds__(256) void agg2_kernel(const int* __restrict__ rowptr, const int* __restrict__ esrc,
                                                   const float* __restrict__ a2s, const float* __restrict__ a2d,
                                                   const unsigned short* __restrict__ gb,
                                                   const float* __restrict__ bias2,
                                                   float* __restrict__ out_sm, float* __restrict__ emb, int N) {
  int wid = (blockIdx.x * 256 + threadIdx.x) >> 6;
  int lane = threadIdx.x & 63;
  if (wid >= N) return;
  int n = wid;
  int c = lane & 15, sub = lane >> 4;
  float ad = a2d[n];
  int beg = rowptr[n], end = rowptr[n + 1];
  float acc = 0.f, wsum = 0.f;
  for (int k = beg + sub; k < end; k += 4) {
    int s = esrc[k];
    float al = a2s[s] + ad;
    al = (al > 0.f) ? al : NEG_SLOPE * al;
    float w = __expf(al);
    acc = fmaf(w, bf2f(gb[(size_t)s * 16 + c]), acc);
    wsum += w;
  }
  acc += __shfl_xor(acc, 16); acc += __shfl_xor(acc, 32);
  wsum += __shfl_xor(wsum, 16); wsum += __shfl_xor(wsum, 32);
  float v = acc / (wsum + EPSF) + bias2[c];
  float m = v;
#pragma unroll
  for (int k2 = 1; k2 < 16; k2 <<= 1) m = fmaxf(m, __shfl_xor(m, k2));
  float e = __expf(v - m);
  float ssum = e;
#pragma unroll
  for (int k2 = 1; k2 < 16; k2 <<= 1) ssum += __shfl_xor(ssum, k2);
  if (sub == 0) {
    emb[(size_t)n * 16 + c] = v;
    out_sm[(size_t)n * 16 + c] = e / ssum;
  }
}

extern "C" void kernel_launch(void* const* d_in, const int* in_sizes, int n_in,
                              void* d_out, int out_size, void* d_ws, size_t ws_size,
                              hipStream_t stream) {
  const float* x     = (const float*)d_in[0];
  const int*   ei    = (const int*)d_in[1];
  const float* W1    = (const float*)d_in[2];
  const float* atts1 = (const float*)d_in[3];
  const float* attd1 = (const float*)d_in[4];
  const float* bias1 = (const float*)d_in[5];
  const float* W2    = (const float*)d_in[6];
  const float* atts2 = (const float*)d_in[7];
  const float* attd2 = (const float*)d_in[8];
  const float* bias2 = (const float*)d_in[9];

  const int N = in_sizes[0] / 512;
  const int E = in_sizes[1] / 2;
  const int ET = E + N;

  // workspace layout (bytes are generous; ws is hundreds of MB)
  char* wp = (char*)d_ws;
  unsigned short* h1b = (unsigned short*)wp;        wp += (size_t)N * 64 * 2;
  float* a1s = (float*)wp;                          wp += (size_t)N * 8 * 4;
  float* a1d = (float*)wp;                          wp += (size_t)N * 8 * 4;
  unsigned short* gb = (unsigned short*)wp;         wp += (size_t)N * 16 * 2;
  float* a2s = (float*)wp;                          wp += (size_t)N * 4;
  float* a2d = (float*)wp;                          wp += (size_t)N * 4;
  int* deg = (int*)wp;                              wp += (size_t)N * 4;
  int* rowptr = (int*)wp;                           wp += (size_t)(N + 1) * 4;
  int* cursor = (int*)wp;                           wp += (size_t)N * 4;
  int* blocksum = (int*)wp;                         wp += 256 * 4;
  int* esrc = (int*)wp;                             wp += (size_t)ET * 4;
  unsigned short* wb = (unsigned short*)wp;         wp += 512 * 64 * 2 * 2;

  float* out_sm = (float*)d_out;            // softmax output [N,16]
  float* emb    = out_sm + (size_t)N * 16;  // node_embeddings [N,16]

  const int nb = (N + 1023) / 1024;

  // CSR build
  init_deg_kernel<<<(N + 255) / 256, 256, 0, stream>>>(deg, N);
  count_kernel<<<(E + 255) / 256, 256, 0, stream>>>(ei, E, deg);
  scan1_kernel<<<nb, 256, 0, stream>>>(deg, blocksum, N);
  scan2_kernel<<<1, 256, 0, stream>>>(blocksum, nb);
  scan3_kernel<<<(N + 256) / 256, 256, 0, stream>>>(deg, blocksum, rowptr, cursor, N, ET);
  scatter_kernel<<<8 * 1024, 256, 0, stream>>>(ei, E, ET, cursor, esrc, N);

  // layer 1: MFMA gemm (async 2-phase) + fused att scalars
  prep_w_kernel<<<128, 256, 0, stream>>>(W1, wb);
  gemm1_kernel<<<(N + 127) / 128, 256, 0, stream>>>(x, wb, atts1, attd1, h1b, a1s, a1d, N);
  agg1_kernel<<<(N + 3) / 4, 256, 0, stream>>>(rowptr, esrc, a1s, a1d, h1b, bias1,
                                               W2, atts2, attd2, gb, a2s, a2d, N);
  agg2_kernel<<<(N + 3) / 4, 256, 0, stream>>>(rowptr, esrc, a2s, a2d, gb, bias2, out_sm, emb, N);
}

// Round 9
// 342.047 us; speedup vs baseline: 1.1690x; 1.1690x over previous
//
#include <hip/hip_runtime.h>
#include <hip/hip_bf16.h>

#define NEG_SLOPE 0.2f
#define EPSF 1e-16f

typedef __attribute__((ext_vector_type(8))) short bf16x8;
typedef __attribute__((ext_vector_type(4))) float f32x4;

__device__ inline unsigned short f2bf(float x) {
  unsigned int u = __float_as_uint(x);
  return (unsigned short)((u + 0x7fffu + ((u >> 16) & 1u)) >> 16);
}
__device__ inline float bf2f(unsigned short h) {
  return __uint_as_float(((unsigned int)h) << 16);
}

__device__ __forceinline__ void gload16(const void* src, void* dst) {
  __builtin_amdgcn_global_load_lds(
      (const __attribute__((address_space(1))) unsigned int*)src,
      (__attribute__((address_space(3))) unsigned int*)dst, 16, 0, 0);
}

// -------------------- W prep: chunked pre-swizzled B slabs --------------------
__global__ __launch_bounds__(256) void prep_w_kernel(const float* __restrict__ W,
                                                     unsigned short* __restrict__ wb) {
  int idx = blockIdx.x * 256 + threadIdx.x;  // (k:512, c:64)
  if (idx >= 512 * 64) return;
  int k = idx >> 6, c = idx & 63;
  float w = W[idx];
  unsigned short h = f2bf(w);
  unsigned short l = f2bf(w - bf2f(h));
  int ch = k >> 5, kin = k & 31;
  int Ap = ((c << 6) + (kin << 1)) ^ ((c & 7) << 4);  // byte in 4KB slab
  wb[ch * 4096 + (Ap >> 1)] = h;
  wb[ch * 4096 + 2048 + (Ap >> 1)] = l;
}

// -------------------- GEMM1 + fused att1: h1b(bf16) = x @ W1; a1s/a1d from f32 acc ----------
__global__ __launch_bounds__(256) void gemm1_kernel(const float* __restrict__ x,
                                                    const unsigned short* __restrict__ wb,
                                                    const float* __restrict__ atts,
                                                    const float* __restrict__ attd,
                                                    unsigned short* __restrict__ h1b,
                                                    float* __restrict__ a1s,
                                                    float* __restrict__ a1d, int N) {
  __shared__ __align__(16) float As[2][4096];          // 2 x 128r x 32k f32 = 32 KB
  __shared__ __align__(16) unsigned short Bs[2][4096]; // 2 x (hi 2048 + lo 2048) = 16 KB
  const int tid = threadIdx.x, wv = tid >> 6, lane = tid & 63;
  const int row0 = blockIdx.x * 128;

  const float* asrc[4];
  int aldo[4];
#pragma unroll
  for (int i = 0; i < 4; ++i) {
    int u = i * 256 + wv * 64 + lane;
    int row = u >> 3, w = u & 7;
    int rg = row0 + row;
    if (rg >= N) rg = N - 1;
    asrc[i] = x + (size_t)rg * 512 + ((w ^ (row & 7)) << 2);
    aldo[i] = (i * 256 + wv * 64) * 4;
  }
  const unsigned short* bsrc[2];
  int bldo[2];
#pragma unroll
  for (int i = 0; i < 2; ++i) {
    int u = i * 256 + wv * 64 + lane;
    bsrc[i] = wb + (size_t)u * 8;
    bldo[i] = (i * 256 + wv * 64) * 8;
  }

  const int kofs = (lane >> 4) * 8;
  const int cbase = lane & 15;
  int ardo[2][2];
#pragma unroll
  for (int rt = 0; rt < 2; ++rt) {
    int r = wv * 32 + rt * 16 + cbase;
#pragma unroll
    for (int h = 0; h < 2; ++h)
      ardo[rt][h] = r * 32 + ((((kofs >> 2) + h) ^ (r & 7)) << 2);
  }
  int brdo[4];
#pragma unroll
  for (int ct = 0; ct < 4; ++ct) {
    int c = ct * 16 + cbase;
    brdo[ct] = (((c << 6) + (kofs << 1)) ^ ((c & 7) << 4)) >> 1;
  }

  f32x4 acc[2][4] = {};

  auto stage = [&](int b, int ch) {
#pragma unroll
    for (int i = 0; i < 4; ++i) gload16(asrc[i] + ch * 32, &As[b][aldo[i]]);
#pragma unroll
    for (int i = 0; i < 2; ++i) gload16(bsrc[i] + ch * 4096, &Bs[b][bldo[i]]);
  };

  stage(0, 0);
  for (int ch = 0; ch < 16; ++ch) {
    const int b = ch & 1;
    if (ch < 15) {
      stage(b ^ 1, ch + 1);
      asm volatile("s_waitcnt vmcnt(6)" ::: "memory");
    } else {
      asm volatile("s_waitcnt vmcnt(0)" ::: "memory");
    }
    __builtin_amdgcn_s_barrier();
    __builtin_amdgcn_sched_barrier(0);

#pragma unroll
    for (int rt = 0; rt < 2; ++rt) {
      float4 a0 = *(const float4*)(&As[b][ardo[rt][0]]);
      float4 a1 = *(const float4*)(&As[b][ardo[rt][1]]);
      float av[8] = {a0.x, a0.y, a0.z, a0.w, a1.x, a1.y, a1.z, a1.w};
      bf16x8 ah, al;
#pragma unroll
      for (int j = 0; j < 8; ++j) {
        unsigned int u = __float_as_uint(av[j]);
        ah[j] = (short)(unsigned short)(u >> 16);
        float lo = av[j] - __uint_as_float(u & 0xffff0000u);
        al[j] = (short)(unsigned short)(__float_as_uint(lo) >> 16);
      }
#pragma unroll
      for (int ct = 0; ct < 4; ++ct) {
        bf16x8 bh = *(const bf16x8*)(&Bs[b][brdo[ct]]);
        bf16x8 bl = *(const bf16x8*)(&Bs[b][brdo[ct] + 2048]);
        acc[rt][ct] = __builtin_amdgcn_mfma_f32_16x16x32_bf16(ah, bh, acc[rt][ct], 0, 0, 0);
        acc[rt][ct] = __builtin_amdgcn_mfma_f32_16x16x32_bf16(al, bh, acc[rt][ct], 0, 0, 0);
        acc[rt][ct] = __builtin_amdgcn_mfma_f32_16x16x32_bf16(ah, bl, acc[rt][ct], 0, 0, 0);
      }
    }
    asm volatile("s_waitcnt lgkmcnt(0)" ::: "memory");
    __builtin_amdgcn_s_barrier();
  }

  float wS[4], wD[4];
#pragma unroll
  for (int ct = 0; ct < 4; ++ct) {
    wS[ct] = atts[ct * 16 + cbase];
    wD[ct] = attd[ct * 16 + cbase];
  }
#pragma unroll
  for (int rt = 0; rt < 2; ++rt) {
#pragma unroll
    for (int ct = 0; ct < 4; ++ct) {
#pragma unroll
      for (int j = 0; j < 4; ++j) {
        int r = row0 + wv * 32 + rt * 16 + (lane >> 4) * 4 + j;
        float a = acc[rt][ct][j];
        if (r < N) h1b[(size_t)r * 64 + ct * 16 + cbase] = f2bf(a);
        float ps = a * wS[ct], pd = a * wD[ct];
        ps += __shfl_xor(ps, 1); pd += __shfl_xor(pd, 1);
        ps += __shfl_xor(ps, 2); pd += __shfl_xor(pd, 2);
        ps += __shfl_xor(ps, 4); pd += __shfl_xor(pd, 4);
        if ((lane & 7) == 0 && r < N) {
          int h = ct * 2 + ((lane >> 3) & 1);
          a1s[r * 8 + h] = ps;
          a1d[r * 8 + h] = pd;
        }
      }
    }
  }
}

// -------------------- CSR build --------------------
__global__ __launch_bounds__(256) void init_deg_kernel(int* __restrict__ deg, int N) {
  int i = blockIdx.x * 256 + threadIdx.x;
  if (i < N) deg[i] = 1;  // self-loop
}

__global__ __launch_bounds__(256) void count_kernel(const int* __restrict__ ei, int E, int* __restrict__ deg) {
  int e = blockIdx.x * 256 + threadIdx.x;
  if (e < E) atomicAdd(&deg[ei[E + e]], 1);
}

__global__ __launch_bounds__(256) void scan1_kernel(int* __restrict__ data, int* __restrict__ blocksum, int N) {
  __shared__ int wave_tot[4];
  int t = threadIdx.x;
  int base = blockIdx.x * 1024;
  int v[4];
  int sum = 0;
#pragma unroll
  for (int i = 0; i < 4; ++i) {
    int idx = base + t * 4 + i;
    v[i] = sum;
    int d = (idx < N) ? data[idx] : 0;
    sum += d;
  }
  int lane = t & 63, wv = t >> 6;
  int x = sum;
#pragma unroll
  for (int ofs = 1; ofs < 64; ofs <<= 1) {
    int y = __shfl_up(x, ofs);
    if (lane >= ofs) x += y;
  }
  if (lane == 63) wave_tot[wv] = x;
  __syncthreads();
  int wofs = 0;
  for (int w = 0; w < wv; ++w) wofs += wave_tot[w];
  int excl_thread = wofs + x - sum;
#pragma unroll
  for (int i = 0; i < 4; ++i) {
    int idx = base + t * 4 + i;
    if (idx < N) data[idx] = excl_thread + v[i];
  }
  if (t == 255) blocksum[blockIdx.x] = wofs + x;
}

__global__ __launch_bounds__(256) void scan2_kernel(int* __restrict__ blocksum, int nb) {
  __shared__ int sm[256];
  int t = threadIdx.x;
  int x = (t < nb) ? blocksum[t] : 0;
  sm[t] = x;
  __syncthreads();
  for (int ofs = 1; ofs < 256; ofs <<= 1) {
    int y = (t >= ofs) ? sm[t - ofs] : 0;
    __syncthreads();
    sm[t] += y;
    __syncthreads();
  }
  if (t < nb) blocksum[t] = sm[t] - x;  // exclusive
}

__global__ __launch_bounds__(256) void scan3_kernel(const int* __restrict__ excl, const int* __restrict__ blocksum,
                                                    int* __restrict__ rowptr, int* __restrict__ cursor,
                                                    int N, int ET) {
  int idx = blockIdx.x * 256 + threadIdx.x;
  if (idx < N) {
    int r = excl[idx] + blocksum[idx >> 10];
    rowptr[idx] = r;
    cursor[idx] = r;
  }
  if (idx == N) rowptr[N] = ET;
}

// XCD-class-filtered scatter (keeps cursor/esrc writes XCD-local)
__global__ __launch_bounds__(256) void scatter_kernel(const int* __restrict__ ei, int E, int ET,
                                                      int* __restrict__ cursor, int* __restrict__ esrc, int N) {
  const int cls = blockIdx.x & 7;
  const int nlo = (int)(((long long)N * cls) >> 3);
  const int nhi = (int)(((long long)N * (cls + 1)) >> 3);
  const int chunk = blockIdx.x >> 3;
  const int nchunks = gridDim.x >> 3;
  const long long stride = (long long)nchunks * 256;
  for (long long e = (long long)chunk * 256 + threadIdx.x; e < ET; e += stride) {
    int s, d;
    if (e < E) { d = ei[E + e]; s = ei[e]; }
    else       { d = (int)(e - E); s = d; }
    if (d >= nlo && d < nhi) {
      int pos = atomicAdd(&cursor[d], 1);
      esrc[pos] = s;
    }
  }
}

// -------------------- agg1: TWO nodes per wave (32 lanes each), lane = 2 channels ----------
// half-wave owns one dst node; lane covers channels (2l, 2l+1) via packed ushort2 gather.
// Writes h2 (bf16) after norm+bias+ELU.
__global__ __launch_bounds__(256) void agg1_kernel(const int* __restrict__ rowptr, const int* __restrict__ esrc,
                                                   const float* __restrict__ a1s, const float* __restrict__ a1d,
                                                   const unsigned short* __restrict__ h1b,
                                                   const float* __restrict__ bias1,
                                                   unsigned short* __restrict__ h2b, int N) {
  const int wid = (blockIdx.x * 256 + threadIdx.x) >> 6;  // wave id
  const int lane = threadIdx.x & 63;
  const int half = lane >> 5, l = lane & 31;
  const int nA = wid * 2;
  if (nA >= N) return;
  const int n = nA + half;
  const bool nvalid = n < N;
  const int nc = nvalid ? n : nA;
  const int h = l >> 2;             // head of channel pair
  const int c2 = l * 2;

  const float ad = a1d[(unsigned)nc * 8 + h];
  const int beg = rowptr[nc];
  const int deg = nvalid ? (rowptr[nc + 1] - beg) : 0;
  const int degO = __shfl_xor(deg, 32);
  const int dmax = max(deg, degO);
  const int dcl = max(deg, 1) - 1;

  float acc0 = 0.f, acc1 = 0.f, wsum = 0.f;
  for (int it = 0; it < dmax; it += 2) {
    int k0 = beg + min(it, dcl);
    int k1 = beg + min(it + 1, dcl);
    float m0 = (it < deg) ? 1.f : 0.f;
    float m1 = (it + 1 < deg) ? 1.f : 0.f;
    int s0 = esrc[k0], s1 = esrc[k1];
    unsigned int g0 = *(const unsigned int*)(h1b + ((unsigned)s0 * 64 + c2));
    unsigned int g1 = *(const unsigned int*)(h1b + ((unsigned)s1 * 64 + c2));
    float al0 = a1s[(unsigned)s0 * 8 + h] + ad;
    float al1 = a1s[(unsigned)s1 * 8 + h] + ad;
    al0 = fmaxf(al0, NEG_SLOPE * al0);
    al1 = fmaxf(al1, NEG_SLOPE * al1);
    float w0 = __expf(al0) * m0;
    float w1 = __expf(al1) * m1;
    acc0 = fmaf(w0, bf2f((unsigned short)(g0 & 0xffff)), acc0);
    acc1 = fmaf(w0, bf2f((unsigned short)(g0 >> 16)), acc1);
    acc0 = fmaf(w1, bf2f((unsigned short)(g1 & 0xffff)), acc0);
    acc1 = fmaf(w1, bf2f((unsigned short)(g1 >> 16)), acc1);
    wsum += w0 + w1;
  }
  float inv = 1.f / (wsum + EPSF);
  float2 b2 = *(const float2*)(bias1 + c2);
  float v0 = acc0 * inv + b2.x;
  float v1 = acc1 * inv + b2.y;
  v0 = (v0 > 0.f) ? v0 : expm1f(v0);
  v1 = (v1 > 0.f) ? v1 : expm1f(v1);
  if (nvalid) {
    unsigned int pack = (unsigned int)f2bf(v0) | ((unsigned int)f2bf(v1) << 16);
    *(unsigned int*)(h2b + ((unsigned)n * 64 + c2)) = pack;
  }
}

// -------------------- layer2 projection g = h2 @ W2 + attention scalars --------------------
__global__ __launch_bounds__(256) void l2_proj_kernel(const unsigned short* __restrict__ h2b,
                                                      const float* __restrict__ W2,
                                                      const float* __restrict__ atts, const float* __restrict__ attd,
                                                      unsigned short* __restrict__ gb, float* __restrict__ a2s,
                                                      float* __restrict__ a2d, int N) {
  __shared__ float w[1024];
  int tid = threadIdx.x;
  for (int i = tid; i < 1024; i += 256) w[i] = W2[i];
  __syncthreads();
  int gid = blockIdx.x * 256 + tid;
  int n = gid >> 4, c = gid & 15;
  if (n >= N) return;
  const unsigned short* hr = h2b + (size_t)n * 64;
  float acc = 0.f;
#pragma unroll
  for (int k8 = 0; k8 < 8; ++k8) {
    bf16x8 hv = *(const bf16x8*)(hr + k8 * 8);
#pragma unroll
    for (int j = 0; j < 8; ++j)
      acc = fmaf(bf2f((unsigned short)hv[j]), w[(k8 * 8 + j) * 16 + c], acc);
  }
  gb[(size_t)n * 16 + c] = f2bf(acc);
  float ps = acc * atts[c], pd = acc * attd[c];
#pragma unroll
  for (int m = 1; m < 16; m <<= 1) { ps += __shfl_xor(ps, m); pd += __shfl_xor(pd, m); }
  if (c == 0) { a2s[n] = ps; a2d[n] = pd; }
}

// -------------------- layer-2 aggregation + bias + softmax (fused final) --------------------
__global__ __launch_bounds__(256) void agg2_kernel(const int* __restrict__ rowptr, const int* __restrict__ esrc,
                                                   const float* __restrict__ a2s, const float* __restrict__ a2d,
                                                   const unsigned short* __restrict__ gb,
                                                   const float* __restrict__ bias2,
                                                   float* __restrict__ out_sm, float* __restrict__ emb, int N) {
  int wid = (blockIdx.x * 256 + threadIdx.x) >> 6;
  int lane = threadIdx.x & 63;
  if (wid >= N) return;
  int n = wid;
  int c = lane & 15, sub = lane >> 4;
  float ad = a2d[n];
  int beg = rowptr[n], end = rowptr[n + 1];
  float acc = 0.f, wsum = 0.f;
  for (int k = beg + sub; k < end; k += 4) {
    int s = esrc[k];
    float al = a2s[s] + ad;
    al = fmaxf(al, NEG_SLOPE * al);
    float w = __expf(al);
    acc = fmaf(w, bf2f(gb[(unsigned)s * 16 + c]), acc);
    wsum += w;
  }
  acc += __shfl_xor(acc, 16); acc += __shfl_xor(acc, 32);
  wsum += __shfl_xor(wsum, 16); wsum += __shfl_xor(wsum, 32);
  float v = acc / (wsum + EPSF) + bias2[c];
  float m = v;
#pragma unroll
  for (int k2 = 1; k2 < 16; k2 <<= 1) m = fmaxf(m, __shfl_xor(m, k2));
  float e = __expf(v - m);
  float ssum = e;
#pragma unroll
  for (int k2 = 1; k2 < 16; k2 <<= 1) ssum += __shfl_xor(ssum, k2);
  if (sub == 0) {
    emb[(size_t)n * 16 + c] = v;
    out_sm[(size_t)n * 16 + c] = e / ssum;
  }
}

extern "C" void kernel_launch(void* const* d_in, const int* in_sizes, int n_in,
                              void* d_out, int out_size, void* d_ws, size_t ws_size,
                              hipStream_t stream) {
  const float* x     = (const float*)d_in[0];
  const int*   ei    = (const int*)d_in[1];
  const float* W1    = (const float*)d_in[2];
  const float* atts1 = (const float*)d_in[3];
  const float* attd1 = (const float*)d_in[4];
  const float* bias1 = (const float*)d_in[5];
  const float* W2    = (const float*)d_in[6];
  const float* atts2 = (const float*)d_in[7];
  const float* attd2 = (const float*)d_in[8];
  const float* bias2 = (const float*)d_in[9];

  const int N = in_sizes[0] / 512;
  const int E = in_sizes[1] / 2;
  const int ET = E + N;

  char* wp = (char*)d_ws;
  unsigned short* h1b = (unsigned short*)wp;        wp += (size_t)N * 64 * 2;
  unsigned short* h2b = (unsigned short*)wp;        wp += (size_t)N * 64 * 2;
  float* a1s = (float*)wp;                          wp += (size_t)N * 8 * 4;
  float* a1d = (float*)wp;                          wp += (size_t)N * 8 * 4;
  unsigned short* gb = (unsigned short*)wp;         wp += (size_t)N * 16 * 2;
  float* a2s = (float*)wp;                          wp += (size_t)N * 4;
  float* a2d = (float*)wp;                          wp += (size_t)N * 4;
  int* deg = (int*)wp;                              wp += (size_t)N * 4;
  int* rowptr = (int*)wp;                           wp += (size_t)(N + 1) * 4;
  int* cursor = (int*)wp;                           wp += (size_t)N * 4;
  int* blocksum = (int*)wp;                         wp += 256 * 4;
  int* esrc = (int*)wp;                             wp += (size_t)ET * 4;
  unsigned short* wb = (unsigned short*)wp;         wp += 512 * 64 * 2 * 2;

  float* out_sm = (float*)d_out;            // softmax output [N,16]
  float* emb    = out_sm + (size_t)N * 16;  // node_embeddings [N,16]

  const int nb = (N + 1023) / 1024;

  // CSR build
  init_deg_kernel<<<(N + 255) / 256, 256, 0, stream>>>(deg, N);
  count_kernel<<<(E + 255) / 256, 256, 0, stream>>>(ei, E, deg);
  scan1_kernel<<<nb, 256, 0, stream>>>(deg, blocksum, N);
  scan2_kernel<<<1, 256, 0, stream>>>(blocksum, nb);
  scan3_kernel<<<(N + 256) / 256, 256, 0, stream>>>(deg, blocksum, rowptr, cursor, N, ET);
  scatter_kernel<<<8 * 1024, 256, 0, stream>>>(ei, E, ET, cursor, esrc, N);

  // layer 1
  prep_w_kernel<<<128, 256, 0, stream>>>(W1, wb);
  gemm1_kernel<<<(N + 127) / 128, 256, 0, stream>>>(x, wb, atts1, attd1, h1b, a1s, a1d, N);
  agg1_kernel<<<(N + 7) / 8, 256, 0, stream>>>(rowptr, esrc, a1s, a1d, h1b, bias1, h2b, N);

  // layer 2
  l2_proj_kernel<<<(N * 16 + 255) / 256, 256, 0, stream>>>(h2b, W2, atts2, attd2, gb, a2s, a2d, N);
  agg2_kernel<<<(N + 3) / 4, 256, 0, stream>>>(rowptr, esrc, a2s, a2d, gb, bias2, out_sm, emb, N);
}